// Round 4
// baseline (595.759 us; speedup 1.0000x reference)
//
#include <hip/hip_runtime.h>
#include <hip/hip_bf16.h>
#include <stdint.h>

#define BATCH 8192
#define IN_F  4096
#define OUT_F 4096

#define BM 128
#define BN 128
#define BK 64
#define THREADS 128

typedef __attribute__((ext_vector_type(8)))  short bf16x8;   // 8 bf16 = 4 VGPRs
typedef __attribute__((ext_vector_type(16))) float f32x16;   // 32x32 MFMA acc

// ---------- helpers ----------

__device__ __forceinline__ unsigned short f2bf(float f) {
    unsigned int u = __float_as_uint(f);
    unsigned int lsb = (u >> 16) & 1u;
    u += 0x7fffu + lsb;
    return (unsigned short)(u >> 16);
}

__device__ __forceinline__ void gl_lds16(const void* g, void* l) {
    // async global->LDS, 16B per lane. HW dest = wave-uniform base + lane*16.
    __builtin_amdgcn_global_load_lds(
        (const __attribute__((address_space(1))) void*)g,
        (__attribute__((address_space(3))) void*)l,
        16, 0, 0);
}

__device__ __forceinline__ int sigma(int row) {
    // bank swizzle: chunk position = g ^ sigma(row). Includes row>>3 so lanes
    // sharing row&7 (which share a bank quad under row&7-only swizzle -> 4-way
    // conflict, measured 3.36e7 in round 3) get distinct chunk positions.
    return (row ^ (row >> 3)) & 7;
}

// ---------- fused convert kernel ----------
#define XBLK ((BATCH * IN_F) / 8 / 256)
#define WBLK ((OUT_F * IN_F) / 8 / 256)

__global__ __launch_bounds__(256) void cvt_kernel(const float4* __restrict__ x,
                                                  const float4* __restrict__ w,
                                                  const float4* __restrict__ m,
                                                  uint4* __restrict__ xo,
                                                  uint4* __restrict__ wo) {
    int b = blockIdx.x;
    union { unsigned short u[8]; uint4 v; } r;
    if (b < XBLK) {
        int i = b * 256 + threadIdx.x;
        float4 a0 = x[2 * i], a1 = x[2 * i + 1];
        r.u[0] = f2bf(a0.x); r.u[1] = f2bf(a0.y); r.u[2] = f2bf(a0.z); r.u[3] = f2bf(a0.w);
        r.u[4] = f2bf(a1.x); r.u[5] = f2bf(a1.y); r.u[6] = f2bf(a1.z); r.u[7] = f2bf(a1.w);
        xo[i] = r.v;
    } else {
        int i = (b - XBLK) * 256 + threadIdx.x;
        float4 wa = w[2 * i], wb = w[2 * i + 1];
        float4 ma = m[2 * i], mb = m[2 * i + 1];
        r.u[0] = f2bf(wa.x * ma.x); r.u[1] = f2bf(wa.y * ma.y);
        r.u[2] = f2bf(wa.z * ma.z); r.u[3] = f2bf(wa.w * ma.w);
        r.u[4] = f2bf(wb.x * mb.x); r.u[5] = f2bf(wb.y * mb.y);
        r.u[6] = f2bf(wb.z * mb.z); r.u[7] = f2bf(wb.w * mb.w);
        wo[i] = r.v;
    }
}

// ---------- GEMM: C[M,N] = A[M,K] * W[N,K]^T + bias ----------
// 128x128 tile, BK=64, TWO waves (128 threads), wave tile 64x128:
// per ks each wave reads 2 A-frags + 4 B-frags (6 KB) feeding 8 MFMAs
// -> LDS:MFMA cycle ratio 0.75:1 (vs 1:1 for the 64x64 wave tile), so the
// MFMA pipe, not LDS, is the long pole. 32 KB LDS/block -> 4 blocks/CU.
// acc = 2x4 f32x16 = 128 VGPRs; launch_bounds(128,2) caps regs at 256.
__global__ __launch_bounds__(THREADS, 2) void gemm_kernel(const unsigned short* __restrict__ A,
                                                          const unsigned short* __restrict__ W,
                                                          const float* __restrict__ bias,
                                                          float* __restrict__ C) {
    __shared__ unsigned short lA[BM * BK];   // 16 KiB
    __shared__ unsigned short lB[BN * BK];   // 16 KiB

    const int tid  = threadIdx.x;
    const int lane = tid & 63;
    const int wave = tid >> 6;        // 0..1
    const int bm = blockIdx.y;
    const int bn = blockIdx.x;

    const int wm  = wave * 64;        // wave's M offset in the 128 tile
    const int r32 = lane & 31;
    const int hi  = lane >> 5;        // k-half within a 16-wide k-step

    f32x16 acc[2][4] = {};

    const unsigned short* Ab = A + (size_t)(bm * BM) * IN_F;
    const unsigned short* Wb = W + (size_t)(bn * BN) * IN_F;

    // staging: 1024 slots of 16B per array; slot s -> row = s>>3, chunk
    // position = s&7 holds global chunk (s&7) ^ sigma(row)
    int goff[8], loff[8];
#pragma unroll
    for (int i = 0; i < 8; ++i) {
        int s = i * THREADS + tid;
        int row = s >> 3;
        int g = (s & 7) ^ sigma(row);
        goff[i] = row * IN_F + g * 8;
        loff[i] = s * 8;              // elements (16B per slot)
    }

    // fragment row bases + swizzle keys (loop-invariant)
    int aoff[2], asig[2], boff[4], bsig[4];
#pragma unroll
    for (int i = 0; i < 2; ++i) {
        int row = wm + i * 32 + r32;
        aoff[i] = row * BK; asig[i] = sigma(row);
    }
#pragma unroll
    for (int j = 0; j < 4; ++j) {
        int row = j * 32 + r32;
        boff[j] = row * BK; bsig[j] = sigma(row);
    }

    for (int kt = 0; kt < IN_F; kt += BK) {
#pragma unroll
        for (int i = 0; i < 8; ++i)
            gl_lds16(Ab + goff[i] + kt, &lA[loff[i]]);
#pragma unroll
        for (int i = 0; i < 8; ++i)
            gl_lds16(Wb + goff[i] + kt, &lB[loff[i]]);
        __syncthreads();   // drains vmcnt (global_load_lds) + barrier

#pragma unroll
        for (int ks = 0; ks < 4; ++ks) {          // 4 k-steps of 16
            const int g = ks * 2 + hi;
            bf16x8 af[2], bfj[4];
#pragma unroll
            for (int i = 0; i < 2; ++i)
                af[i] = *(const bf16x8*)&lA[aoff[i] + ((g ^ asig[i]) << 3)];
#pragma unroll
            for (int j = 0; j < 4; ++j)
                bfj[j] = *(const bf16x8*)&lB[boff[j] + ((g ^ bsig[j]) << 3)];
#pragma unroll
            for (int j = 0; j < 4; ++j)
#pragma unroll
                for (int i = 0; i < 2; ++i)
                    acc[i][j] = __builtin_amdgcn_mfma_f32_32x32x16_bf16(
                        af[i], bfj[j], acc[i][j], 0, 0, 0);
        }
        __syncthreads();
    }

    // epilogue: 32x32 C/D layout: col = lane&31, row = (reg&3)+8*(reg>>2)+4*(lane>>5)
    const int crow0 = bm * BM + wm;
    const int ccol0 = bn * BN;
#pragma unroll
    for (int j = 0; j < 4; ++j) {
        const int col = ccol0 + j * 32 + r32;
        const float bj = bias[col];
#pragma unroll
        for (int i = 0; i < 2; ++i) {
#pragma unroll
            for (int reg = 0; reg < 16; ++reg) {
                int row = crow0 + i * 32 + (reg & 3) + 8 * (reg >> 2) + 4 * hi;
                C[(size_t)row * OUT_F + col] = acc[i][j][reg] + bj;
            }
        }
    }
}

// ---------- fallback (no workspace): correct-but-slow fp32 path ----------
__global__ __launch_bounds__(256) void fallback_kernel(const float* __restrict__ x,
                                                       const float* __restrict__ w,
                                                       const float* __restrict__ bias,
                                                       const float* __restrict__ m,
                                                       float* __restrict__ out) {
    size_t idx = (size_t)blockIdx.x * 256 + threadIdx.x;   // over BATCH*OUT_F
    int row = (int)(idx >> 12);
    int col = (int)(idx & (OUT_F - 1));
    const float4* xr = (const float4*)(x + (size_t)row * IN_F);
    const float4* wr = (const float4*)(w + (size_t)col * IN_F);
    const float4* mr = (const float4*)(m + (size_t)col * IN_F);
    float s = 0.f;
    for (int k = 0; k < IN_F / 4; ++k) {
        float4 xv = xr[k], wv = wr[k], mv = mr[k];
        s += xv.x * wv.x * mv.x + xv.y * wv.y * mv.y +
             xv.z * wv.z * mv.z + xv.w * wv.w * mv.w;
    }
    out[idx] = s + bias[col];
}

// ---------- launch ----------

extern "C" void kernel_launch(void* const* d_in, const int* in_sizes, int n_in,
                              void* d_out, int out_size, void* d_ws, size_t ws_size,
                              hipStream_t stream) {
    const float* x    = (const float*)d_in[0];
    const float* w    = (const float*)d_in[1];
    const float* bias = (const float*)d_in[2];
    const float* mask = (const float*)d_in[3];
    float* out = (float*)d_out;

    const size_t need = ((size_t)BATCH * IN_F + (size_t)OUT_F * IN_F) * sizeof(unsigned short);
    if (ws_size < need) {
        fallback_kernel<<<(size_t)BATCH * OUT_F / 256, 256, 0, stream>>>(
            x, w, bias, mask, out);
        return;
    }

    unsigned short* xb = (unsigned short*)d_ws;
    unsigned short* wb = xb + (size_t)BATCH * IN_F;

    cvt_kernel<<<XBLK + WBLK, 256, 0, stream>>>(
        (const float4*)x, (const float4*)w, (const float4*)mask,
        (uint4*)xb, (uint4*)wb);

    dim3 grid(OUT_F / BN, BATCH / BM);   // 32 x 64 = 2048 blocks
    gemm_kernel<<<grid, THREADS, 0, stream>>>(xb, wb, bias, out);
}